// Round 2
// baseline (8981.889 us; speedup 1.0000x reference)
//
#include <hip/hip_runtime.h>
#include <cstdint>

typedef unsigned short u16;
typedef __attribute__((ext_vector_type(8))) short short8;
typedef __attribute__((ext_vector_type(4))) float f32x4;

#define B_ 16
#define P_ 128
#define T_ 16384
#define F_ 64
#define H_ 256
#define O_ 32
#define MBLK 16
#define NBLOCKS 128
#define NTHREADS 512

// workspace layout (bytes)
#define WS_STARTS 0         // 2048 * int32
#define WS_WIH0   8192      // 64 tiles * KF2 * 512 bf16 = 131072 B
#define WS_WHH0   139264    // 64 * 8 * 512 * 2 = 524288 B
#define WS_WIH1   663552
#define WS_WHH1   1187840
#define WS_WFC    1712128   // 2 * 8 * 512 * 2 = 16384 B
#define WS_B0     1728512   // 1024 fp32
#define WS_B1     1732608

#define HOFF 8388608LL              // out_final floats
#define COFF 9437184LL              // HOFF + 2*2048*256

__device__ __forceinline__ u16 f2bf(float f) {
  uint32_t u = __float_as_uint(f);
  u += 0x7FFFu + ((u >> 16) & 1u);
  return (u16)(u >> 16);
}
__device__ __forceinline__ float sigm(float x) { return 1.f / (1.f + __expf(-x)); }
__device__ __forceinline__ float tanhf_(float x) {
  float e = __expf(-2.f * fabsf(x));
  float t = (1.f - e) / (1.f + e);
  return x < 0.f ? -t : t;
}

// per-batch exclusive prefix sum of path lengths
__global__ void k_starts(const int* __restrict__ lpp, int* __restrict__ starts) {
  int b = threadIdx.x;
  if (b >= B_) return;
  int run = 0;
  for (int p = 0; p < P_; p++) { starts[b * P_ + p] = run; run += lpp[b * P_ + p]; }
}

// pack weight matrix into fragment-major bf16 layout:
// flat idx = ((tile*KF + kf)*512 + lane*8 + i)
// element = W[row][k], k = kf*32 + (lane>>4)*8 + i
// perm=1: tile = wave*8 + nt; row = (nt&3)*256 + wave*32 + ((nt>>2)<<4) + (lane&15)
// perm=0: row = tile*16 + (lane&15)
__global__ void k_pack(const float* __restrict__ W, u16* __restrict__ o,
                       int ntiles, int KF, int K, int perm) {
  int idx = blockIdx.x * 256 + threadIdx.x;
  if (idx >= ntiles * KF * 512) return;
  int i = idx & 7;
  int lane = (idx >> 3) & 63;
  int rem = idx >> 9;
  int kf = rem % KF, tile = rem / KF;
  int c = lane & 15, kg = lane >> 4;
  int row;
  if (perm) { int wv = tile >> 3, nt = tile & 7; row = (nt & 3) * 256 + wv * 32 + ((nt >> 2) << 4) + c; }
  else row = tile * 16 + c;
  int k = kf * 32 + kg * 8 + i;
  o[idx] = f2bf(W[(long long)row * K + k]);
}

__global__ void k_bias(const float* bih0, const float* bhh0,
                       const float* bih1, const float* bhh1,
                       float* b0, float* b1) {
  int n = blockIdx.x * 256 + threadIdx.x;
  if (n >= 1024) return;
  int wv = n >> 7, r = n & 127, nt = r >> 4, c = n & 15;
  int row = (nt & 3) * 256 + wv * 32 + ((nt >> 2) << 4) + c;
  b0[n] = bih0[row] + bhh0[row];
  b1[n] = bih1[row] + bhh1[row];
}

__launch_bounds__(NTHREADS, 2)
__global__ void lstm_main(const float* __restrict__ x,
                          const int* __restrict__ lpp,
                          const float* __restrict__ bfc,
                          const uint8_t* __restrict__ ws,
                          float* __restrict__ out) {
  const int g = blockIdx.x;
  const int tid = threadIdx.x;
  const int w = tid >> 6;        // wave 0..7, owns permuted gate cols [w*128, w*128+128)
  const int lane = tid & 63;
  const int lr = lane & 15;      // A-row / B-col within tile
  const int lg = lane >> 4;      // k-group; D rows lg*4..lg*4+3

  __shared__ __align__(16) u16 x_lds[16][72];          // pad 8 to stagger banks
  __shared__ __align__(16) u16 h0_lds[2][16][264];
  __shared__ __align__(16) u16 h1_lds[2][16][264];
  __shared__ __align__(16) u16 y0_lds[16][264];
  __shared__ __align__(16) u16 y1_lds[16][264];
  __shared__ int len_s[16];
  __shared__ int start_s[16];
  __shared__ int bb_s[16];

  const int* starts = (const int*)(ws + WS_STARTS);
  if (tid < 16) {
    int sg = g * MBLK + tid;
    len_s[tid] = lpp[sg];
    start_s[tid] = starts[sg];
    bb_s[tid] = sg >> 7;   // P_=128 paths per batch
  }
  for (int i = tid; i < 16 * 264; i += NTHREADS) {
    ((u16*)h0_lds)[i] = 0;   // zero buffer 0 of each
    ((u16*)h1_lds)[i] = 0;
  }
  __syncthreads();

  int maxlen = 0;
  #pragma unroll
  for (int i = 0; i < 16; i++) maxlen = max(maxlen, len_s[i]);

  // per-lane row info (D rows = seqs lg*4+v)
  int len_r[4];
  long long obase[4];
  #pragma unroll
  for (int v = 0; v < 4; v++) {
    int r = lg * 4 + v;
    len_r[v] = len_s[r];
    obase[v] = ((long long)bb_s[r] * T_ + start_s[r]) * O_ + (w & 1) * 16 + lr;
  }

  // x staging assignment: thread -> (seq, 2 floats)
  const int sseq = tid >> 5;
  const int sk2 = (tid & 31) << 1;
  const int slen = len_s[sseq];
  const float* xptr = x + ((long long)bb_s[sseq] * T_ + start_s[sseq]) * F_ + sk2;
  uint32_t* xdst = (uint32_t*)&x_lds[sseq][sk2];

  const float* b0p = (const float*)(ws + WS_B0);
  const float* b1p = (const float*)(ws + WS_B1);
  float b0r[8], b1r[8];
  #pragma unroll
  for (int nt = 0; nt < 8; nt++) {
    b0r[nt] = b0p[w * 128 + nt * 16 + lr];
    b1r[nt] = b1p[w * 128 + nt * 16 + lr];
  }
  const u16* wih0 = (const u16*)(ws + WS_WIH0) + (w * 8) * 2 * 512 + lane * 8;
  const u16* whh0 = (const u16*)(ws + WS_WHH0) + (w * 8) * 8 * 512 + lane * 8;
  const u16* wih1 = (const u16*)(ws + WS_WIH1) + (w * 8) * 8 * 512 + lane * 8;
  const u16* whh1 = (const u16*)(ws + WS_WHH1) + (w * 8) * 8 * 512 + lane * 8;
  const u16* wfc  = (const u16*)(ws + WS_WFC) + lane * 8;
  float bfc_r = (w < 2) ? bfc[w * 16 + lr] : 0.f;

  // B-fragment loaders (register double-buffer targets)
  auto loadL0 = [&](short8* d, int nt) {
    d[0] = *(const short8*)(wih0 + ((nt * 2 + 0) << 9));
    d[1] = *(const short8*)(wih0 + ((nt * 2 + 1) << 9));
    #pragma unroll
    for (int kf = 0; kf < 8; kf++)
      d[2 + kf] = *(const short8*)(whh0 + ((nt * 8 + kf) << 9));
  };
  auto loadL1 = [&](short8* d, int c) {   // c=0..15: nt=c>>1, half: 0=wih1(ay), 1=whh1(ah)
    int nt = c >> 1;
    const u16* base = (c & 1) ? whh1 : wih1;
    #pragma unroll
    for (int kf = 0; kf < 8; kf++)
      d[kf] = *(const short8*)(base + ((nt * 8 + kf) << 9));
  };

  float h0r[8], c0r[8], h1r[8], c1r[8];   // [h2*4 + v]
  #pragma unroll
  for (int i = 0; i < 8; i++) { h0r[i] = 0.f; c0r[i] = 0.f; h1r[i] = 0.f; c1r[i] = 0.f; }

  for (int t = 0; t < maxlen; t++) {
    // ---- stage x_t (bf16) ----
    {
      float xa = 0.f, xb = 0.f;
      if (t < slen) {
        float2 xv = *(const float2*)(xptr + (long long)t * F_);
        xa = xv.x; xb = xv.y;
      }
      *xdst = (uint32_t)f2bf(xa) | ((uint32_t)f2bf(xb) << 16);
    }
    __syncthreads();
    const int cur = t & 1, nxt = cur ^ 1;

    // ---- layer 0: gates = x@Wih0^T + h0@Whh0^T + bias ----
    {
      short8 ax0 = *(const short8*)&x_lds[lr][lg * 8];
      short8 ax1 = *(const short8*)&x_lds[lr][32 + lg * 8];
      short8 ah[8];
      #pragma unroll
      for (int kf = 0; kf < 8; kf++)
        ah[kf] = *(const short8*)&h0_lds[cur][lr][kf * 32 + lg * 8];
      f32x4 acc[8];
      short8 fA[10], fB[10];
      loadL0(fA, 0);
      #pragma unroll
      for (int nt = 0; nt < 8; nt++) {
        short8* curf = (nt & 1) ? fB : fA;
        short8* nxtf = (nt & 1) ? fA : fB;
        if (nt < 7) loadL0(nxtf, nt + 1);
        f32x4 a = {0.f, 0.f, 0.f, 0.f};
        a = __builtin_amdgcn_mfma_f32_16x16x32_bf16(ax0, curf[0], a, 0, 0, 0);
        a = __builtin_amdgcn_mfma_f32_16x16x32_bf16(ax1, curf[1], a, 0, 0, 0);
        #pragma unroll
        for (int kf = 0; kf < 8; kf++)
          a = __builtin_amdgcn_mfma_f32_16x16x32_bf16(ah[kf], curf[2 + kf], a, 0, 0, 0);
        acc[nt] = a;
      }
      #pragma unroll
      for (int h2 = 0; h2 < 2; h2++) {
        #pragma unroll
        for (int v = 0; v < 4; v++) {
          float gi = acc[h2 * 4 + 0][v] + b0r[h2 * 4 + 0];
          float gf = acc[h2 * 4 + 1][v] + b0r[h2 * 4 + 1];
          float gg = acc[h2 * 4 + 2][v] + b0r[h2 * 4 + 2];
          float go = acc[h2 * 4 + 3][v] + b0r[h2 * 4 + 3];
          float ii = sigm(gi), ff = sigm(gf), gv = tanhf_(gg), oo = sigm(go);
          float cn = ff * c0r[h2 * 4 + v] + ii * gv;
          float hn = oo * tanhf_(cn);
          bool m = (t < len_r[v]);
          if (m) { c0r[h2 * 4 + v] = cn; h0r[h2 * 4 + v] = hn; }
          u16 hb = f2bf(h0r[h2 * 4 + v]);
          int r = lg * 4 + v, col = w * 32 + h2 * 16 + lr;
          h0_lds[nxt][r][col] = hb;
          y0_lds[r][col] = m ? hb : (u16)0;
        }
      }
    }
    __syncthreads();

    // ---- layer 1: gates = y0@Wih1^T + h1@Whh1^T + bias ----
    {
      short8 ay[8], ah[8];
      #pragma unroll
      for (int kf = 0; kf < 8; kf++) {
        ay[kf] = *(const short8*)&y0_lds[lr][kf * 32 + lg * 8];
        ah[kf] = *(const short8*)&h1_lds[cur][lr][kf * 32 + lg * 8];
      }
      f32x4 acc[8];
      #pragma unroll
      for (int nt = 0; nt < 8; nt++) acc[nt] = (f32x4){0.f, 0.f, 0.f, 0.f};
      short8 fA[8], fB[8];
      loadL1(fA, 0);
      #pragma unroll
      for (int c = 0; c < 16; c++) {
        short8* curf = (c & 1) ? fB : fA;
        short8* nxtf = (c & 1) ? fA : fB;
        if (c < 15) loadL1(nxtf, c + 1);
        const int nt = c >> 1;
        if (c & 1) {
          #pragma unroll
          for (int kf = 0; kf < 8; kf++)
            acc[nt] = __builtin_amdgcn_mfma_f32_16x16x32_bf16(ah[kf], curf[kf], acc[nt], 0, 0, 0);
        } else {
          #pragma unroll
          for (int kf = 0; kf < 8; kf++)
            acc[nt] = __builtin_amdgcn_mfma_f32_16x16x32_bf16(ay[kf], curf[kf], acc[nt], 0, 0, 0);
        }
      }
      #pragma unroll
      for (int h2 = 0; h2 < 2; h2++) {
        #pragma unroll
        for (int v = 0; v < 4; v++) {
          float gi = acc[h2 * 4 + 0][v] + b1r[h2 * 4 + 0];
          float gf = acc[h2 * 4 + 1][v] + b1r[h2 * 4 + 1];
          float gg = acc[h2 * 4 + 2][v] + b1r[h2 * 4 + 2];
          float go = acc[h2 * 4 + 3][v] + b1r[h2 * 4 + 3];
          float ii = sigm(gi), ff = sigm(gf), gv = tanhf_(gg), oo = sigm(go);
          float cn = ff * c1r[h2 * 4 + v] + ii * gv;
          float hn = oo * tanhf_(cn);
          bool m = (t < len_r[v]);
          if (m) { c1r[h2 * 4 + v] = cn; h1r[h2 * 4 + v] = hn; }
          u16 hb = f2bf(h1r[h2 * 4 + v]);
          int r = lg * 4 + v, col = w * 32 + h2 * 16 + lr;
          h1_lds[nxt][r][col] = hb;
          y1_lds[r][col] = m ? hb : (u16)0;
        }
      }
    }
    __syncthreads();

    // ---- FC: out = y1 @ Wfc^T + bfc (waves 0,1 only) ----
    if (w < 2) {
      f32x4 a = {0.f, 0.f, 0.f, 0.f};
      #pragma unroll
      for (int kf = 0; kf < 8; kf++) {
        short8 ayv = *(const short8*)&y1_lds[lr][kf * 32 + lg * 8];
        a = __builtin_amdgcn_mfma_f32_16x16x32_bf16(ayv, *(const short8*)(wfc + ((w * 8 + kf) << 9)), a, 0, 0, 0);
      }
      #pragma unroll
      for (int v = 0; v < 4; v++)
        if (t < len_r[v])
          __builtin_nontemporal_store(a[v] + bfc_r, &out[obase[v] + (long long)t * O_]);
    }
  }

  // ---- final states: h_t (2,2048,256), c_t (2,2048,256) ----
  #pragma unroll
  for (int h2 = 0; h2 < 2; h2++) {
    #pragma unroll
    for (int v = 0; v < 4; v++) {
      int r = lg * 4 + v;
      long long sg = (long long)g * MBLK + r;
      int j = w * 32 + h2 * 16 + lr;
      __builtin_nontemporal_store(h0r[h2 * 4 + v], &out[HOFF + sg * H_ + j]);
      __builtin_nontemporal_store(h1r[h2 * 4 + v], &out[HOFF + 524288 + sg * H_ + j]);
      __builtin_nontemporal_store(c0r[h2 * 4 + v], &out[COFF + sg * H_ + j]);
      __builtin_nontemporal_store(c1r[h2 * 4 + v], &out[COFF + 524288 + sg * H_ + j]);
    }
  }
}

extern "C" void kernel_launch(void* const* d_in, const int* in_sizes, int n_in,
                              void* d_out, int out_size, void* d_ws, size_t ws_size,
                              hipStream_t stream) {
  const float* x    = (const float*)d_in[0];
  const int*   lpp  = (const int*)d_in[2];
  const float* Wih0 = (const float*)d_in[4];
  const float* Whh0 = (const float*)d_in[5];
  const float* bih0 = (const float*)d_in[6];
  const float* bhh0 = (const float*)d_in[7];
  const float* Wih1 = (const float*)d_in[8];
  const float* Whh1 = (const float*)d_in[9];
  const float* bih1 = (const float*)d_in[10];
  const float* bhh1 = (const float*)d_in[11];
  const float* Wfc  = (const float*)d_in[12];
  const float* bfc  = (const float*)d_in[13];
  uint8_t* ws = (uint8_t*)d_ws;
  float* out = (float*)d_out;

  // zero the scatter target region (rest of out is fully overwritten)
  hipMemsetAsync(d_out, 0, 8388608ull * 4, stream);

  k_starts<<<1, 16, 0, stream>>>(lpp, (int*)(ws + WS_STARTS));
  k_pack<<<256, 256, 0, stream>>>(Wih0, (u16*)(ws + WS_WIH0), 64, 2, 64, 1);
  k_pack<<<1024, 256, 0, stream>>>(Whh0, (u16*)(ws + WS_WHH0), 64, 8, 256, 1);
  k_pack<<<1024, 256, 0, stream>>>(Wih1, (u16*)(ws + WS_WIH1), 64, 8, 256, 1);
  k_pack<<<1024, 256, 0, stream>>>(Whh1, (u16*)(ws + WS_WHH1), 64, 8, 256, 1);
  k_pack<<<32, 256, 0, stream>>>(Wfc, (u16*)(ws + WS_WFC), 2, 8, 256, 0);
  k_bias<<<4, 256, 0, stream>>>(bih0, bhh0, bih1, bhh1,
                                (float*)(ws + WS_B0), (float*)(ws + WS_B1));
  lstm_main<<<NBLOCKS, NTHREADS, 0, stream>>>(x, lpp, bfc, ws, out);
}

// Round 3
// 7996.135 us; speedup vs baseline: 1.1233x; 1.1233x over previous
//
#include <hip/hip_runtime.h>
#include <cstdint>

typedef unsigned short u16;
typedef __attribute__((ext_vector_type(8))) short short8;
typedef __attribute__((ext_vector_type(4))) float f32x4;

#define B_ 16
#define P_ 128
#define T_ 16384
#define H_ 256
#define O_ 32
#define MBLK 16
#define NBLOCKS 128
#define NTHREADS 512

// workspace layout (bytes)
#define WS_STARTS 0         // 2048 * int32
#define WS_B0     8192      // 1024 fp32
#define WS_B1     12288     // 1024 fp32
#define WS_STREAM 16384     // 8 waves * 27 phases * 4096 u16 * 2B = 1769472 B

#define HOFF 8388608LL      // h_t offset in out (floats)
#define COFF 9437184LL      // c_t offset

#define SBAR0 __builtin_amdgcn_sched_barrier(0)
#define LGKM0 asm volatile("s_waitcnt lgkmcnt(0)" ::: "memory")
#define WAITV8 asm volatile("s_waitcnt vmcnt(8)" ::: "memory")
#define BLOCK_BARRIER() do { SBAR0; LGKM0; __builtin_amdgcn_s_barrier(); SBAR0; } while (0)

__device__ __forceinline__ u16 f2bf(float f) {
  uint32_t u = __float_as_uint(f);
  u += 0x7FFFu + ((u >> 16) & 1u);
  return (u16)(u >> 16);
}
__device__ __forceinline__ float sigm(float x) { return 1.f / (1.f + __expf(-x)); }
__device__ __forceinline__ float tanhf_(float x) {
  float e = __expf(-2.f * fabsf(x));
  float t = (1.f - e) / (1.f + e);
  return x < 0.f ? -t : t;
}

__global__ void k_starts(const int* __restrict__ lpp, int* __restrict__ starts) {
  int b = threadIdx.x;
  if (b >= B_) return;
  int run = 0;
  for (int p = 0; p < P_; p++) { starts[b * P_ + p] = run; run += lpp[b * P_ + p]; }
}

// Pack all weights into one contiguous per-wave phase stream:
// idx = ((wv*27 + p)*8 + f)*512 + lane*8 + i
// phases: 0-1 wih0, 2-9 whh0, 10-17 wih1, 18-25 whh1, 26 wfc
__global__ void k_pack_stream(const float* __restrict__ Wih0, const float* __restrict__ Whh0,
                              const float* __restrict__ Wih1, const float* __restrict__ Whh1,
                              const float* __restrict__ Wfc, u16* __restrict__ o) {
  int idx = blockIdx.x * 256 + threadIdx.x;
  if (idx >= 8 * 27 * 4096) return;
  int i = idx & 7;
  int lane = (idx >> 3) & 63;
  int f = (idx >> 9) & 7;
  int pp = idx >> 12;
  int p = pp % 27, wv = pp / 27;
  int c = lane & 15, kg = lane >> 4, k = kg * 8 + i;
  float val;
  if (p < 2)        { int nt = p * 4 + (f >> 1), kf = f & 1;
                      int row = (nt & 3) * 256 + wv * 32 + ((nt >> 2) << 4) + c;
                      val = Wih0[row * 64 + kf * 32 + k]; }
  else if (p < 10)  { int nt = p - 2;
                      int row = (nt & 3) * 256 + wv * 32 + ((nt >> 2) << 4) + c;
                      val = Whh0[row * 256 + f * 32 + k]; }
  else if (p < 18)  { int nt = p - 10;
                      int row = (nt & 3) * 256 + wv * 32 + ((nt >> 2) << 4) + c;
                      val = Wih1[row * 256 + f * 32 + k]; }
  else if (p < 26)  { int nt = p - 18;
                      int row = (nt & 3) * 256 + wv * 32 + ((nt >> 2) << 4) + c;
                      val = Whh1[row * 256 + f * 32 + k]; }
  else              { int tile = wv & 1; int row = tile * 16 + c;
                      val = Wfc[row * 256 + f * 32 + k]; }
  o[idx] = f2bf(val);
}

__global__ void k_bias(const float* bih0, const float* bhh0,
                       const float* bih1, const float* bhh1,
                       float* b0, float* b1) {
  int n = blockIdx.x * 256 + threadIdx.x;
  if (n >= 1024) return;
  int wv = n >> 7, r = n & 127, nt = r >> 4, c = n & 15;
  int row = (nt & 3) * 256 + wv * 32 + ((nt >> 2) << 4) + c;
  b0[n] = bih0[row] + bhh0[row];
  b1[n] = bih1[row] + bhh1[row];
}

__launch_bounds__(NTHREADS, 2)
__global__ void lstm_main(const float* __restrict__ x,
                          const int* __restrict__ lpp,
                          const float* __restrict__ bfc,
                          const uint8_t* __restrict__ ws,
                          float* __restrict__ out) {
  const int g = blockIdx.x;
  const int tid = threadIdx.x;
  const int w = tid >> 6;
  const int lane = tid & 63;
  const int lr = lane & 15;
  const int lg = lane >> 4;

  __shared__ __align__(16) u16 stage[8][2][4096];  // [wave][slot][8 frags * 512]
  __shared__ __align__(16) u16 h0p[16][264];
  __shared__ __align__(16) u16 h1p[16][264];
  __shared__ int len_s[16];
  __shared__ int start_s[16];
  __shared__ int bb_s[16];

  const int* starts = (const int*)(ws + WS_STARTS);
  if (tid < 16) {
    int sg = g * MBLK + tid;
    len_s[tid] = lpp[sg];
    start_s[tid] = starts[sg];
    bb_s[tid] = sg >> 7;
  }
  for (int i = tid; i < 16 * 264; i += NTHREADS) {
    ((u16*)h0p)[i] = 0;
    ((u16*)h1p)[i] = 0;
  }
  __syncthreads();   // prologue only — before any DMA traffic

  int maxlen = 0;
  #pragma unroll
  for (int i = 0; i < 16; i++) maxlen = max(maxlen, len_s[i]);

  int len_r[4];
  long long obase[4];
  #pragma unroll
  for (int v = 0; v < 4; v++) {
    int r = lg * 4 + v;
    len_r[v] = len_s[r];
    obase[v] = ((long long)bb_s[r] * T_ + start_s[r]) * O_ + (w & 1) * 16 + lr;
  }

  const float* b0p = (const float*)(ws + WS_B0);
  const float* b1p = (const float*)(ws + WS_B1);
  float b0r[8], b1r[8];
  #pragma unroll
  for (int nt = 0; nt < 8; nt++) {
    b0r[nt] = b0p[w * 128 + nt * 16 + lr];
    b1r[nt] = b1p[w * 128 + nt * 16 + lr];
  }
  float bfc_r = (w < 2) ? bfc[w * 16 + lr] : 0.f;

  // per-lane x row pointer (A-frag row = seq lr, k-cols lg*8..)
  const float* xrow = x + ((long long)bb_s[lr] * T_ + start_s[lr]) * 64 + lg * 8;
  const int lenrow = len_s[lr];

  // per-wave weight stream (lane offset folded in)
  const u16* stream_w = (const u16*)(ws + WS_STREAM) + (size_t)w * 27 * 4096 + lane * 8;

  auto ISSUE = [&](int pid) {
    int ap = (pid == 27) ? 1 : pid;   // dummy phase 27 re-issues phase 1's data
    const u16* gp = stream_w + ap * 4096;
    const u16* lpb = &stage[w][pid & 1][0];
    #pragma unroll
    for (int f = 0; f < 8; f++)
      __builtin_amdgcn_global_load_lds(
          (const __attribute__((address_space(1))) void*)(gp + f * 512),
          (__attribute__((address_space(3))) void*)(lpb + f * 512), 16, 0, 0);
  };
  #define RD(p, f) (*(const short8*)&stage[w][(p) & 1][(f) * 512 + lane * 8])

  float4 xn0, xn1, xn2, xn3;
  auto XLOAD = [&](int t) {
    const float* pb = xrow + (long long)((t < lenrow) ? t : 0) * 64;
    xn0 = *(const float4*)(pb);
    xn1 = *(const float4*)(pb + 4);
    xn2 = *(const float4*)(pb + 32);
    xn3 = *(const float4*)(pb + 36);
  };
  auto mk8 = [&](float4 a, float4 b) {
    short8 r;
    r[0] = (short)f2bf(a.x); r[1] = (short)f2bf(a.y);
    r[2] = (short)f2bf(a.z); r[3] = (short)f2bf(a.w);
    r[4] = (short)f2bf(b.x); r[5] = (short)f2bf(b.y);
    r[6] = (short)f2bf(b.z); r[7] = (short)f2bf(b.w);
    return r;
  };

  float h0r[8], c0r[8], h1r[8], c1r[8];
  #pragma unroll
  for (int i = 0; i < 8; i++) { h0r[i] = 0.f; c0r[i] = 0.f; h1r[i] = 0.f; c1r[i] = 0.f; }

  // prologue: x(0) first (oldest in queue), then prefetch phases 0,1
  XLOAD(0);
  ISSUE(0);
  ISSUE(1);

  for (int t = 0; t < maxlen; t++) {
    short8 xa0 = mk8(xn0, xn1);
    short8 xa1 = mk8(xn2, xn3);

    short8 ah0[8], ah1[8];
    #pragma unroll
    for (int kf = 0; kf < 8; kf++) {
      ah0[kf] = *(const short8*)&h0p[lr][kf * 32 + lg * 8];
      ah1[kf] = *(const short8*)&h1p[lr][kf * 32 + lg * 8];
    }
    BLOCK_BARRIER();   // A: all reads of h planes done before any writes this step

    f32x4 acc0[8];
    #pragma unroll
    for (int nt = 0; nt < 8; nt++) acc0[nt] = (f32x4){0.f, 0.f, 0.f, 0.f};

    // phases 0-1: wih0  (acc0[nt] += x * W)
    #pragma unroll
    for (int p = 0; p < 2; p++) {
      WAITV8;
      short8 rf[8];
      #pragma unroll
      for (int f = 0; f < 8; f++) rf[f] = RD(p, f);
      LGKM0; SBAR0;
      ISSUE(p + 2);
      #pragma unroll
      for (int f = 0; f < 8; f++) {
        int nt = p * 4 + (f >> 1);
        acc0[nt] = __builtin_amdgcn_mfma_f32_16x16x32_bf16((f & 1) ? xa1 : xa0, rf[f], acc0[nt], 0, 0, 0);
      }
    }
    // phases 2-9: whh0
    #pragma unroll
    for (int p = 2; p < 10; p++) {
      WAITV8;
      short8 rf[8];
      #pragma unroll
      for (int f = 0; f < 8; f++) rf[f] = RD(p, f);
      LGKM0; SBAR0;
      ISSUE(p + 2);
      const int nt = p - 2;
      #pragma unroll
      for (int f = 0; f < 8; f++)
        acc0[nt] = __builtin_amdgcn_mfma_f32_16x16x32_bf16(ah0[f], rf[f], acc0[nt], 0, 0, 0);
    }

    // cell 0 -> write h0 plane
    #pragma unroll
    for (int h2 = 0; h2 < 2; h2++) {
      #pragma unroll
      for (int v = 0; v < 4; v++) {
        float gi = acc0[h2 * 4 + 0][v] + b0r[h2 * 4 + 0];
        float gf = acc0[h2 * 4 + 1][v] + b0r[h2 * 4 + 1];
        float gg = acc0[h2 * 4 + 2][v] + b0r[h2 * 4 + 2];
        float go = acc0[h2 * 4 + 3][v] + b0r[h2 * 4 + 3];
        float ii = sigm(gi), ff = sigm(gf), gv = tanhf_(gg), oo = sigm(go);
        float cn = ff * c0r[h2 * 4 + v] + ii * gv;
        float hn = oo * tanhf_(cn);
        if (t < len_r[v]) { c0r[h2 * 4 + v] = cn; h0r[h2 * 4 + v] = hn; }
        h0p[lg * 4 + v][w * 32 + h2 * 16 + lr] = f2bf(h0r[h2 * 4 + v]);
      }
    }
    BLOCK_BARRIER();   // B: h0 plane (y0) visible

    short8 ay[8];
    #pragma unroll
    for (int kf = 0; kf < 8; kf++)
      ay[kf] = *(const short8*)&h0p[lr][kf * 32 + lg * 8];

    XLOAD(t + 1);      // next-step x; retires under the remaining phases

    f32x4 acc1[8];
    #pragma unroll
    for (int nt = 0; nt < 8; nt++) acc1[nt] = (f32x4){0.f, 0.f, 0.f, 0.f};

    // phases 10-17: wih1 (A = y0)
    #pragma unroll
    for (int p = 10; p < 18; p++) {
      WAITV8;
      short8 rf[8];
      #pragma unroll
      for (int f = 0; f < 8; f++) rf[f] = RD(p, f);
      LGKM0; SBAR0;
      ISSUE(p + 2);
      const int nt = p - 10;
      #pragma unroll
      for (int f = 0; f < 8; f++)
        acc1[nt] = __builtin_amdgcn_mfma_f32_16x16x32_bf16(ay[f], rf[f], acc1[nt], 0, 0, 0);
    }
    // phases 18-25: whh1 (A = h1 prev)
    #pragma unroll
    for (int p = 18; p < 26; p++) {
      WAITV8;
      short8 rf[8];
      #pragma unroll
      for (int f = 0; f < 8; f++) rf[f] = RD(p, f);
      LGKM0; SBAR0;
      ISSUE(p + 2);                      // p==25 issues pid 27 (dummy dup of phase 1)
      const int nt = p - 18;
      #pragma unroll
      for (int f = 0; f < 8; f++)
        acc1[nt] = __builtin_amdgcn_mfma_f32_16x16x32_bf16(ah1[f], rf[f], acc1[nt], 0, 0, 0);
    }

    // cell 1 -> write h1 plane
    #pragma unroll
    for (int h2 = 0; h2 < 2; h2++) {
      #pragma unroll
      for (int v = 0; v < 4; v++) {
        float gi = acc1[h2 * 4 + 0][v] + b1r[h2 * 4 + 0];
        float gf = acc1[h2 * 4 + 1][v] + b1r[h2 * 4 + 1];
        float gg = acc1[h2 * 4 + 2][v] + b1r[h2 * 4 + 2];
        float go = acc1[h2 * 4 + 3][v] + b1r[h2 * 4 + 3];
        float ii = sigm(gi), ff = sigm(gf), gv = tanhf_(gg), oo = sigm(go);
        float cn = ff * c1r[h2 * 4 + v] + ii * gv;
        float hn = oo * tanhf_(cn);
        if (t < len_r[v]) { c1r[h2 * 4 + v] = cn; h1r[h2 * 4 + v] = hn; }
        h1p[lg * 4 + v][w * 32 + h2 * 16 + lr] = f2bf(h1r[h2 * 4 + v]);
      }
    }
    BLOCK_BARRIER();   // C: h1 plane (y1) visible

    // phase 26: wfc (A = y1)
    WAITV8;
    if (w < 2) {
      short8 rf[8], ay1[8];
      #pragma unroll
      for (int f = 0; f < 8; f++) {
        ay1[f] = *(const short8*)&h1p[lr][f * 32 + lg * 8];
        rf[f] = RD(26, f);
      }
      LGKM0;
      SBAR0;
      ISSUE(0);                          // next step's phase 0 (slot 0, just consumed)
      f32x4 a = {0.f, 0.f, 0.f, 0.f};
      #pragma unroll
      for (int f = 0; f < 8; f++)
        a = __builtin_amdgcn_mfma_f32_16x16x32_bf16(ay1[f], rf[f], a, 0, 0, 0);
      #pragma unroll
      for (int v = 0; v < 4; v++)
        if (t < len_r[v])
          __builtin_nontemporal_store(a[v] + bfc_r, &out[obase[v] + (long long)t * O_]);
    } else {
      SBAR0;
      ISSUE(0);
    }
    ISSUE(1);                            // dummy phase 27 body: issue next step's phase 1
  }

  // final states
  #pragma unroll
  for (int h2 = 0; h2 < 2; h2++) {
    #pragma unroll
    for (int v = 0; v < 4; v++) {
      int r = lg * 4 + v;
      long long sg = (long long)g * MBLK + r;
      int j = w * 32 + h2 * 16 + lr;
      __builtin_nontemporal_store(h0r[h2 * 4 + v], &out[HOFF + sg * H_ + j]);
      __builtin_nontemporal_store(h1r[h2 * 4 + v], &out[HOFF + 524288 + sg * H_ + j]);
      __builtin_nontemporal_store(c0r[h2 * 4 + v], &out[COFF + sg * H_ + j]);
      __builtin_nontemporal_store(c1r[h2 * 4 + v], &out[COFF + 524288 + sg * H_ + j]);
    }
  }
}

extern "C" void kernel_launch(void* const* d_in, const int* in_sizes, int n_in,
                              void* d_out, int out_size, void* d_ws, size_t ws_size,
                              hipStream_t stream) {
  const float* x    = (const float*)d_in[0];
  const int*   lpp  = (const int*)d_in[2];
  const float* Wih0 = (const float*)d_in[4];
  const float* Whh0 = (const float*)d_in[5];
  const float* bih0 = (const float*)d_in[6];
  const float* bhh0 = (const float*)d_in[7];
  const float* Wih1 = (const float*)d_in[8];
  const float* Whh1 = (const float*)d_in[9];
  const float* bih1 = (const float*)d_in[10];
  const float* bhh1 = (const float*)d_in[11];
  const float* Wfc  = (const float*)d_in[12];
  const float* bfc  = (const float*)d_in[13];
  uint8_t* ws = (uint8_t*)d_ws;
  float* out = (float*)d_out;

  hipMemsetAsync(d_out, 0, 8388608ull * 4, stream);

  k_starts<<<1, 16, 0, stream>>>(lpp, (int*)(ws + WS_STARTS));
  k_pack_stream<<<(8 * 27 * 4096 + 255) / 256, 256, 0, stream>>>(
      Wih0, Whh0, Wih1, Whh1, Wfc, (u16*)(ws + WS_STREAM));
  k_bias<<<4, 256, 0, stream>>>(bih0, bhh0, bih1, bhh1,
                                (float*)(ws + WS_B0), (float*)(ws + WS_B1));
  lstm_main<<<NBLOCKS, NTHREADS, 0, stream>>>(x, lpp, bfc, ws, out);
}

// Round 5
// 2758.252 us; speedup vs baseline: 3.2564x; 2.8990x over previous
//
#include <hip/hip_runtime.h>
#include <cstdint>

typedef unsigned short u16;
typedef __attribute__((ext_vector_type(8))) short short8;
typedef __attribute__((ext_vector_type(4))) float f32x4;

#define B_ 16
#define P_ 128
#define T_ 16384
#define H_ 256
#define O_ 32
#define MBLK 16
#define NBLOCKS 128
#define NTHREADS 512

// workspace layout (bytes)
#define WS_STARTS 0         // 2048 * int32
#define WS_B0     8192      // 1024 fp32
#define WS_B1     12288     // 1024 fp32
#define WS_STREAM 16384     // 8 waves * 27 phases * 4096 u16 * 2B = 1769472 B

#define HOFF 8388608LL      // h_t offset in out (floats)
#define COFF 9437184LL      // c_t offset

#define SBAR0 __builtin_amdgcn_sched_barrier(0)
#define LGKM0 asm volatile("s_waitcnt lgkmcnt(0)" ::: "memory")
#define BLOCK_BARRIER() do { SBAR0; LGKM0; __builtin_amdgcn_s_barrier(); SBAR0; } while (0)

// counted vmcnt gate: memory clobber + sched_barrier(0) pins all consumers below
// (rule #18: sched_barrier is the only thing that stops reg-only MFMA hoisting)
#define WAITV(NSTR) do { \
  asm volatile("s_waitcnt vmcnt(" NSTR ")" ::: "memory"); SBAR0; } while (0)

// weight fragment load: straight to VGPRs, invisible to compiler's vmcnt tracking
#define GL(dst, vo, IMMSTR) \
  asm volatile("global_load_dwordx4 %0, %1, %2 offset:" IMMSTR \
               : "=v"(dst) : "v"(vo), "s"(wbv))
#define LOADPH(bq, voff) do { \
  uint32_t vo_ = (voff); uint32_t vo2_ = vo_ + 4096u; \
  GL(bq[0], vo_,  "0");    GL(bq[1], vo_,  "1024"); \
  GL(bq[2], vo_,  "2048"); GL(bq[3], vo_,  "3072"); \
  GL(bq[4], vo2_, "0");    GL(bq[5], vo2_, "1024"); \
  GL(bq[6], vo2_, "2048"); GL(bq[7], vo2_, "3072"); } while (0)

#define GLX(dst, vo, IMMSTR) \
  asm volatile("global_load_dwordx4 %0, %1, %2 offset:" IMMSTR \
               : "=v"(dst) : "v"(vo), "s"(xbv))

// output store: inline asm so the compiler never emits its own vmcnt waits
#define GSTORE(ptr, val) \
  asm volatile("global_store_dword %0, %1, off" :: "v"(ptr), "v"(val))

__device__ __forceinline__ u16 f2bf(float f) {
  uint32_t u = __float_as_uint(f);
  u += 0x7FFFu + ((u >> 16) & 1u);
  return (u16)(u >> 16);
}
__device__ __forceinline__ float sigm(float x) { return 1.f / (1.f + __expf(-x)); }
__device__ __forceinline__ float tanhf_(float x) {
  float e = __expf(-2.f * fabsf(x));
  float t = (1.f - e) / (1.f + e);
  return x < 0.f ? -t : t;
}

__global__ void k_starts(const int* __restrict__ lpp, int* __restrict__ starts) {
  int b = threadIdx.x;
  if (b >= B_) return;
  int run = 0;
  for (int p = 0; p < P_; p++) { starts[b * P_ + p] = run; run += lpp[b * P_ + p]; }
}

// Pack all weights into one contiguous per-wave phase stream:
// idx = ((wv*27 + p)*8 + f)*512 + lane*8 + i
// phases: 0-1 wih0, 2-9 whh0, 10-17 wih1, 18-25 whh1, 26 wfc
__global__ void k_pack_stream(const float* __restrict__ Wih0, const float* __restrict__ Whh0,
                              const float* __restrict__ Wih1, const float* __restrict__ Whh1,
                              const float* __restrict__ Wfc, u16* __restrict__ o) {
  int idx = blockIdx.x * 256 + threadIdx.x;
  if (idx >= 8 * 27 * 4096) return;
  int i = idx & 7;
  int lane = (idx >> 3) & 63;
  int f = (idx >> 9) & 7;
  int pp = idx >> 12;
  int p = pp % 27, wv = pp / 27;
  int c = lane & 15, kg = lane >> 4, k = kg * 8 + i;
  float val;
  if (p < 2)        { int nt = p * 4 + (f >> 1), kf = f & 1;
                      int row = (nt & 3) * 256 + wv * 32 + ((nt >> 2) << 4) + c;
                      val = Wih0[row * 64 + kf * 32 + k]; }
  else if (p < 10)  { int nt = p - 2;
                      int row = (nt & 3) * 256 + wv * 32 + ((nt >> 2) << 4) + c;
                      val = Whh0[row * 256 + f * 32 + k]; }
  else if (p < 18)  { int nt = p - 10;
                      int row = (nt & 3) * 256 + wv * 32 + ((nt >> 2) << 4) + c;
                      val = Wih1[row * 256 + f * 32 + k]; }
  else if (p < 26)  { int nt = p - 18;
                      int row = (nt & 3) * 256 + wv * 32 + ((nt >> 2) << 4) + c;
                      val = Whh1[row * 256 + f * 32 + k]; }
  else              { int tile = wv & 1; int row = tile * 16 + c;
                      val = Wfc[row * 256 + f * 32 + k]; }
  o[idx] = f2bf(val);
}

__global__ void k_bias(const float* bih0, const float* bhh0,
                       const float* bih1, const float* bhh1,
                       float* b0, float* b1) {
  int n = blockIdx.x * 256 + threadIdx.x;
  if (n >= 1024) return;
  int wv = n >> 7, r = n & 127, nt = r >> 4, c = n & 15;
  int row = (nt & 3) * 256 + wv * 32 + ((nt >> 2) << 4) + c;
  b0[n] = bih0[row] + bhh0[row];
  b1[n] = bih1[row] + bhh1[row];
}

__launch_bounds__(NTHREADS, 1)
__global__ void lstm_main(const float* __restrict__ x,
                          const int* __restrict__ lpp,
                          const float* __restrict__ bfc,
                          const uint8_t* __restrict__ ws,
                          float* __restrict__ out) {
  const int g = blockIdx.x;
  const int tid = threadIdx.x;
  const int w = tid >> 6;
  const int lane = tid & 63;
  const int lr = lane & 15;
  const int lg = lane >> 4;

  __shared__ __align__(16) u16 h0p[16][264];
  __shared__ __align__(16) u16 h1p[16][264];
  __shared__ int len_s[16];
  __shared__ int start_s[16];
  __shared__ int bb_s[16];

  const int* starts = (const int*)(ws + WS_STARTS);
  if (tid < 16) {
    int sg = g * MBLK + tid;
    len_s[tid] = lpp[sg];
    start_s[tid] = starts[sg];
    bb_s[tid] = sg >> 7;
  }
  for (int i = tid; i < 16 * 264; i += NTHREADS) {
    ((u16*)h0p)[i] = 0;
    ((u16*)h1p)[i] = 0;
  }
  __syncthreads();   // prologue only — nothing in flight yet

  int maxlen = 0;
  #pragma unroll
  for (int i = 0; i < 16; i++) maxlen = max(maxlen, len_s[i]);

  int len_r[4];
  long long obase[4];
  #pragma unroll
  for (int v = 0; v < 4; v++) {
    int r = lg * 4 + v;
    len_r[v] = len_s[r];
    obase[v] = ((long long)bb_s[r] * T_ + start_s[r]) * O_ + (w & 1) * 16 + lr;
  }

  const float* b0p = (const float*)(ws + WS_B0);
  const float* b1p = (const float*)(ws + WS_B1);
  float b0r[8], b1r[8];
  #pragma unroll
  for (int nt = 0; nt < 8; nt++) {
    b0r[nt] = b0p[w * 128 + nt * 16 + lr];
    b1r[nt] = b1p[w * 128 + nt * 16 + lr];
  }
  float bfc_r = (w < 2) ? bfc[w * 16 + lr] : 0.f;

  const unsigned long long wbv = (unsigned long long)(ws + WS_STREAM);
  const unsigned long long xbv = (unsigned long long)x;
  const uint32_t lane_voff = ((uint32_t)w * 27u * 4096u + (uint32_t)lane * 8u) * 2u;
  const int lenrow = len_s[lr];
  const uint32_t xvbase =
      ((uint32_t)bb_s[lr] * (uint32_t)T_ + (uint32_t)start_s[lr]) * 256u + (uint32_t)lg * 32u;

  float h0r[8], c0r[8], h1r[8], c1r[8];
  #pragma unroll
  for (int i = 0; i < 8; i++) { h0r[i] = 0.f; c0r[i] = 0.f; h1r[i] = 0.f; c1r[i] = 0.f; }

  short8 wb3[3][8];
  float4 xn0, xn1, xn2, xn3;

  // prologue: L(0), X(0), L(1), L(2)  — matches steady-state issue order
  LOADPH(wb3[0], lane_voff + 0u * 8192u);
  {
    uint32_t vox = xvbase;   // t=0 always valid (len >= 1)
    GLX(xn0, vox, "0"); GLX(xn1, vox, "16"); GLX(xn2, vox, "128"); GLX(xn3, vox, "144");
  }
  LOADPH(wb3[1], lane_voff + 1u * 8192u);
  LOADPH(wb3[2], lane_voff + 2u * 8192u);

  for (int t = 0; t < maxlen; t++) {
    // ---- consume x (issued at prev phase 24 / prologue): queue = L,X,L,L ----
    WAITV("16");
    short8 xa0, xa1;
    {
      float xf[8];
      xf[0]=xn0.x; xf[1]=xn0.y; xf[2]=xn0.z; xf[3]=xn0.w;
      xf[4]=xn1.x; xf[5]=xn1.y; xf[6]=xn1.z; xf[7]=xn1.w;
      #pragma unroll
      for (int i = 0; i < 8; i++) xa0[i] = (short)f2bf(xf[i]);
      xf[0]=xn2.x; xf[1]=xn2.y; xf[2]=xn2.z; xf[3]=xn2.w;
      xf[4]=xn3.x; xf[5]=xn3.y; xf[6]=xn3.z; xf[7]=xn3.w;
      #pragma unroll
      for (int i = 0; i < 8; i++) xa1[i] = (short)f2bf(xf[i]);
    }

    short8 ah0[8];
    #pragma unroll
    for (int kf = 0; kf < 8; kf++)
      ah0[kf] = *(const short8*)&h0p[lr][kf * 32 + lg * 8];
    BLOCK_BARRIER();   // A: h-plane reads done before any writes this step

    f32x4 acc0[8];
    #pragma unroll
    for (int nt = 0; nt < 8; nt++) acc0[nt] = (f32x4){0.f, 0.f, 0.f, 0.f};

    // phases 0-1: wih0
    #pragma unroll
    for (int p = 0; p < 2; p++) {
      short8* bp = wb3[p];           // p%3 == p here
      if (p == 0) { WAITV("20"); } else { WAITV("16"); }
      short8 rf[8];
      #pragma unroll
      for (int f = 0; f < 8; f++) rf[f] = bp[f];
      LOADPH(bp, lane_voff + (uint32_t)(p + 3) * 8192u);
      #pragma unroll
      for (int f = 0; f < 8; f++) {
        int nt = p * 4 + (f >> 1);
        acc0[nt] = __builtin_amdgcn_mfma_f32_16x16x32_bf16((f & 1) ? xa1 : xa0, rf[f], acc0[nt], 0, 0, 0);
      }
    }
    // phases 2-9: whh0
    #pragma unroll
    for (int p = 2; p < 10; p++) {
      short8* bp = wb3[p % 3];
      WAITV("16");
      short8 rf[8];
      #pragma unroll
      for (int f = 0; f < 8; f++) rf[f] = bp[f];
      LOADPH(bp, lane_voff + (uint32_t)(p + 3) * 8192u);
      #pragma unroll
      for (int f = 0; f < 8; f++)
        acc0[p - 2] = __builtin_amdgcn_mfma_f32_16x16x32_bf16(ah0[f], rf[f], acc0[p - 2], 0, 0, 0);
    }

    // cell 0 -> write h0 plane; read h1 before barrier B (writes to h1p are post-B)
    #pragma unroll
    for (int h2 = 0; h2 < 2; h2++) {
      #pragma unroll
      for (int v = 0; v < 4; v++) {
        float gi = acc0[h2 * 4 + 0][v] + b0r[h2 * 4 + 0];
        float gf = acc0[h2 * 4 + 1][v] + b0r[h2 * 4 + 1];
        float gg = acc0[h2 * 4 + 2][v] + b0r[h2 * 4 + 2];
        float go = acc0[h2 * 4 + 3][v] + b0r[h2 * 4 + 3];
        float ii = sigm(gi), ff = sigm(gf), gv = tanhf_(gg), oo = sigm(go);
        float cn = ff * c0r[h2 * 4 + v] + ii * gv;
        float hn = oo * tanhf_(cn);
        if (t < len_r[v]) { c0r[h2 * 4 + v] = cn; h0r[h2 * 4 + v] = hn; }
        h0p[lg * 4 + v][w * 32 + h2 * 16 + lr] = f2bf(h0r[h2 * 4 + v]);
      }
    }
    short8 ah1[8];
    #pragma unroll
    for (int kf = 0; kf < 8; kf++)
      ah1[kf] = *(const short8*)&h1p[lr][kf * 32 + lg * 8];
    BLOCK_BARRIER();   // B: h0 plane (y0) visible; h1 reads done

    short8 ay[8];
    #pragma unroll
    for (int kf = 0; kf < 8; kf++)
      ay[kf] = *(const short8*)&h0p[lr][kf * 32 + lg * 8];

    f32x4 acc1[8];
    #pragma unroll
    for (int nt = 0; nt < 8; nt++) acc1[nt] = (f32x4){0.f, 0.f, 0.f, 0.f};

    // phases 10-17: wih1 (A = y0)
    #pragma unroll
    for (int p = 10; p < 18; p++) {
      short8* bp = wb3[p % 3];
      WAITV("16");
      short8 rf[8];
      #pragma unroll
      for (int f = 0; f < 8; f++) rf[f] = bp[f];
      LOADPH(bp, lane_voff + (uint32_t)(p + 3) * 8192u);
      #pragma unroll
      for (int f = 0; f < 8; f++)
        acc1[p - 10] = __builtin_amdgcn_mfma_f32_16x16x32_bf16(ay[f], rf[f], acc1[p - 10], 0, 0, 0);
    }
    // phases 18-25: whh1 (A = h1 prev); phase 24 also issues next-step x
    #pragma unroll
    for (int p = 18; p < 26; p++) {
      short8* bp = wb3[p % 3];
      if (p >= 25) { WAITV("20"); } else { WAITV("16"); }
      short8 rf[8];
      #pragma unroll
      for (int f = 0; f < 8; f++) rf[f] = bp[f];
      LOADPH(bp, lane_voff + (uint32_t)((p + 3) % 27) * 8192u);
      if (p == 24) {
        int tn = t + 1;
        int tt = (tn < lenrow) ? tn : 0;
        uint32_t vox = xvbase + (uint32_t)tt * 256u;
        GLX(xn0, vox, "0"); GLX(xn1, vox, "16"); GLX(xn2, vox, "128"); GLX(xn3, vox, "144");
      }
      #pragma unroll
      for (int f = 0; f < 8; f++)
        acc1[p - 18] = __builtin_amdgcn_mfma_f32_16x16x32_bf16(ah1[f], rf[f], acc1[p - 18], 0, 0, 0);
    }

    // cell 1 -> write h1 plane
    #pragma unroll
    for (int h2 = 0; h2 < 2; h2++) {
      #pragma unroll
      for (int v = 0; v < 4; v++) {
        float gi = acc1[h2 * 4 + 0][v] + b1r[h2 * 4 + 0];
        float gf = acc1[h2 * 4 + 1][v] + b1r[h2 * 4 + 1];
        float gg = acc1[h2 * 4 + 2][v] + b1r[h2 * 4 + 2];
        float go = acc1[h2 * 4 + 3][v] + b1r[h2 * 4 + 3];
        float ii = sigm(gi), ff = sigm(gf), gv = tanhf_(gg), oo = sigm(go);
        float cn = ff * c1r[h2 * 4 + v] + ii * gv;
        float hn = oo * tanhf_(cn);
        if (t < len_r[v]) { c1r[h2 * 4 + v] = cn; h1r[h2 * 4 + v] = hn; }
        h1p[lg * 4 + v][w * 32 + h2 * 16 + lr] = f2bf(h1r[h2 * 4 + v]);
      }
    }
    BLOCK_BARRIER();   // C: h1 plane (y1) visible

    // phase 26: wfc (A = y1) — all waves wait+issue (uniform vmcnt protocol)
    {
      short8* bp = wb3[2];          // 26 % 3 == 2
      WAITV("20");
      short8 rf[8];
      #pragma unroll
      for (int f = 0; f < 8; f++) rf[f] = bp[f];
      LOADPH(bp, lane_voff + 2u * 8192u);   // next step's phase 2
      if (w < 2) {
        short8 ay1[8];
        #pragma unroll
        for (int f = 0; f < 8; f++)
          ay1[f] = *(const short8*)&h1p[lr][f * 32 + lg * 8];
        f32x4 a = {0.f, 0.f, 0.f, 0.f};
        #pragma unroll
        for (int f = 0; f < 8; f++)
          a = __builtin_amdgcn_mfma_f32_16x16x32_bf16(ay1[f], rf[f], a, 0, 0, 0);
        #pragma unroll
        for (int v = 0; v < 4; v++) {
          float val = a[v] + bfc_r;
          const float* p_ = &out[obase[v] + (long long)t * O_];
          if (t < len_r[v]) GSTORE(p_, val);
        }
      }
    }
  }

  asm volatile("s_waitcnt vmcnt(0) lgkmcnt(0)" ::: "memory");
  SBAR0;

  // final states
  #pragma unroll
  for (int h2 = 0; h2 < 2; h2++) {
    #pragma unroll
    for (int v = 0; v < 4; v++) {
      int r = lg * 4 + v;
      long long sg = (long long)g * MBLK + r;
      int j = w * 32 + h2 * 16 + lr;
      __builtin_nontemporal_store(h0r[h2 * 4 + v], &out[HOFF + sg * H_ + j]);
      __builtin_nontemporal_store(h1r[h2 * 4 + v], &out[HOFF + 524288 + sg * H_ + j]);
      __builtin_nontemporal_store(c0r[h2 * 4 + v], &out[COFF + sg * H_ + j]);
      __builtin_nontemporal_store(c1r[h2 * 4 + v], &out[COFF + 524288 + sg * H_ + j]);
    }
  }
}

extern "C" void kernel_launch(void* const* d_in, const int* in_sizes, int n_in,
                              void* d_out, int out_size, void* d_ws, size_t ws_size,
                              hipStream_t stream) {
  const float* x    = (const float*)d_in[0];
  const int*   lpp  = (const int*)d_in[2];
  const float* Wih0 = (const float*)d_in[4];
  const float* Whh0 = (const float*)d_in[5];
  const float* bih0 = (const float*)d_in[6];
  const float* bhh0 = (const float*)d_in[7];
  const float* Wih1 = (const float*)d_in[8];
  const float* Whh1 = (const float*)d_in[9];
  const float* bih1 = (const float*)d_in[10];
  const float* bhh1 = (const float*)d_in[11];
  const float* Wfc  = (const float*)d_in[12];
  const float* bfc  = (const float*)d_in[13];
  uint8_t* ws = (uint8_t*)d_ws;
  float* out = (float*)d_out;

  (void)hipMemsetAsync(d_out, 0, 8388608ull * 4, stream);

  k_starts<<<1, 16, 0, stream>>>(lpp, (int*)(ws + WS_STARTS));
  k_pack_stream<<<(8 * 27 * 4096 + 255) / 256, 256, 0, stream>>>(
      Wih0, Whh0, Wih1, Whh1, Wfc, (u16*)(ws + WS_STREAM));
  k_bias<<<4, 256, 0, stream>>>(bih0, bhh0, bih1, bhh1,
                                (float*)(ws + WS_B0), (float*)(ws + WS_B1));
  lstm_main<<<NBLOCKS, NTHREADS, 0, stream>>>(x, lpp, bfc, ws, out);
}